// Round 1
// baseline (20275.470 us; speedup 1.0000x reference)
//
#include <hip/hip_runtime.h>
#include <hip/hip_bf16.h>

// Persistent wavefront-pipelined 3-layer LSTM + projection for MI355X.
// Stages: L1 (WG 0..47), L2 (48..95), L3 (96..143), Proj (144).
// At global step s: L1 computes t=s, L2 t=s-1, L3 t=s-2, Proj t=s-3.
// Weights resident in VGPRs as MFMA B-fragments; h passed via depth-2 rings
// in ws with agent-scope fences + a flag-based grid barrier per step.

#define T_SEQ 1024
#define NB    64
#define HIDN  768
#define INW   512
#define NOUT  100
#define NWG   145

typedef unsigned int u32;
typedef unsigned short u16;
typedef short bf16x8 __attribute__((ext_vector_type(8)));
typedef float f32x4  __attribute__((ext_vector_type(4)));

// ---- ws layout (ushort element offsets for weights) ----
#define OFF_WIH1 0
#define OFF_WHH1 1572864     // 3072*512
#define OFF_WIH2 3932160     // +3072*768
#define OFF_WHH2 6291456
#define OFF_WIH3 8650752
#define OFF_WHH3 11010048
#define OFF_WP   13369344
#define W_TOTAL  13455360    // + 112*768 (Wp padded to 112 rows)
#define RING_BYTE_OFF (W_TOTAL * 2)            // 26,910,720
#define SLOT_ELEMS 49152                       // 64*768 bf16
#define RING_ELEMS (2 * SLOT_ELEMS)
#define RINGS_BYTES (5 * RING_ELEMS * 2)       // 983,040
#define BAR_BYTES 2048

__device__ __forceinline__ u16 f2b(float f) {
  u32 x = __builtin_bit_cast(u32, f);
  x += 0x7fff + ((x >> 16) & 1);               // round-to-nearest-even
  return (u16)(x >> 16);
}
__device__ __forceinline__ float b2f(u16 u) {
  u32 x = ((u32)u) << 16;
  return __builtin_bit_cast(float, x);
}
__device__ __forceinline__ u32 pack2(float lo, float hi) {
  return (u32)f2b(lo) | ((u32)f2b(hi) << 16);
}
__device__ __forceinline__ float sigf(float x) { return 1.f / (1.f + __expf(-x)); }
__device__ __forceinline__ float tanhf_(float x) {
  float e = __expf(-2.f * fabsf(x));
  float r = (1.f - e) / (1.f + e);
  return x >= 0.f ? r : -r;
}

// -------- prep: fp32 -> bf16 weight conversion (Wp padded to 112 rows) ----
__global__ void prep_weights(const float* __restrict__ Wih1, const float* __restrict__ Whh1,
                             const float* __restrict__ Wih2, const float* __restrict__ Whh2,
                             const float* __restrict__ Wih3, const float* __restrict__ Whh3,
                             const float* __restrict__ Wp, u16* __restrict__ wb) {
  int i = blockIdx.x * 256 + threadIdx.x;
  if (i >= W_TOTAL) return;
  float v;
  if (i < OFF_WHH1)      v = Wih1[i];
  else if (i < OFF_WIH2) v = Whh1[i - OFF_WHH1];
  else if (i < OFF_WHH2) v = Wih2[i - OFF_WIH2];
  else if (i < OFF_WIH3) v = Whh2[i - OFF_WHH2];
  else if (i < OFF_WHH3) v = Wih3[i - OFF_WIH3];
  else if (i < OFF_WP)   v = Whh3[i - OFF_WHH3];
  else {
    int j = i - OFF_WP;
    v = (j < NOUT * HIDN) ? Wp[j] : 0.f;       // rows 100..111 zero-padded
  }
  wb[i] = f2b(v);
}

struct __align__(16) SharedMem {
  u16   Ach[2][64 * 128];   // 32 KB double-buffered A chunk [64 rows][128 k] (XOR-swizzled atoms)
  float Xg[8 * 1024];       // 32 KB cross-wave gate exchange [wave][b(64)][j(16)]
  float c_lds[1024];        // 4 KB fp32 cell state [b][j]
  float bias_lds[64];       // [gate][j]
};

__device__ void grid_barrier(u32* flags, u32* release, int wg, u32 target) {
  __syncthreads();
  const int tid = threadIdx.x;
  if (tid == 0) {
    __threadfence();  // agent release: push ring writes past local L2
    __hip_atomic_store(&flags[wg], target, __ATOMIC_RELEASE, __HIP_MEMORY_SCOPE_AGENT);
  }
  if (wg == NWG - 1) {  // master
    __syncthreads();
    if (tid < NWG) {
      while (__hip_atomic_load(&flags[tid], __ATOMIC_RELAXED, __HIP_MEMORY_SCOPE_AGENT) < target)
        __builtin_amdgcn_s_sleep(2);
    }
    __syncthreads();
    if (tid == 0)
      __hip_atomic_store(release, target, __ATOMIC_RELEASE, __HIP_MEMORY_SCOPE_AGENT);
  }
  if (tid == 0) {
    while (__hip_atomic_load(release, __ATOMIC_RELAXED, __HIP_MEMORY_SCOPE_AGENT) < target)
      __builtin_amdgcn_s_sleep(2);
    __threadfence();  // agent acquire: invalidate L1/L2 before reading fresh rings
  }
  __syncthreads();
}

template <int STAGE>
__device__ void stage_loop(SharedMem* sm,
                           const float* __restrict__ x,      // STAGE 0 only
                           const float* __restrict__ bias,   // b1/b2/b3
                           const u16* __restrict__ Wlo,      // Wih_l (or Wp for proj)
                           const u16* __restrict__ Whi,      // Whh_l
                           const u16* __restrict__ ringIn,   // upstream input ring
                           u16* __restrict__ ringOwn,        // own h ring (read prev, write cur)
                           const u16* __restrict__ ringRes,  // residual re-read ring
                           u16* __restrict__ ringSum,        // residual-sum output ring
                           float* __restrict__ out,          // proj only
                           u32* flags, u32* release, int wg, int j0) {
  constexpr int NCH  = (STAGE == 0) ? 10 : (STAGE == 3 ? 6 : 12);
  constexpr int HALF = (STAGE == 0) ? 5 : 6;
  constexpr int NKT  = (STAGE == 0) ? 20 : 24;

  const int tid  = threadIdx.x;
  const int lane = tid & 63;
  const int w    = tid >> 6;
  const int l15  = lane & 15;
  const int q    = lane >> 4;
  const int g    = w & 3;   // gate (i,f,g,o)
  const int kh   = w >> 2;  // K-half

  if (STAGE < 3) {
    sm->c_lds[tid] = 0.f;
    sm->c_lds[tid + 512] = 0.f;
    if (tid < 64) sm->bias_lds[tid] = bias[(tid >> 4) * HIDN + j0 + (tid & 15)];
  }
  __syncthreads();

  // ---- load resident B fragments (weights) into VGPRs ----
  bf16x8 bfrag[NKT];
  if constexpr (STAGE == 0) {
    int nrow = g * HIDN + j0 + l15;
#pragma unroll
    for (int kt = 0; kt < 20; ++kt) {
      const u16* p;
      if (kh == 0) {
        if (kt < 16) p = Wlo + (size_t)nrow * INW  + kt * 32 + q * 8;          // Wih1, k=0..511
        else         p = Whi + (size_t)nrow * HIDN + (kt - 16) * 32 + q * 8;   // Whh1, k=0..127
      } else         p = Whi + (size_t)nrow * HIDN + 128 + kt * 32 + q * 8;    // Whh1, k=128..767
      bfrag[kt] = *(const bf16x8*)p;
    }
  } else if constexpr (STAGE == 3) {
    int nrow = w * 16 + l15; if (nrow > 111) nrow = 111;   // wave 7 unused
#pragma unroll
    for (int kt = 0; kt < 24; ++kt)
      bfrag[kt] = *(const bf16x8*)(Wlo + (size_t)nrow * HIDN + kt * 32 + q * 8);
  } else {
    int nrow = g * HIDN + j0 + l15;
#pragma unroll
    for (int kt = 0; kt < 24; ++kt) {
      const u16* p = (kh == 0) ? (Wlo + (size_t)nrow * HIDN + kt * 32 + q * 8)
                               : (Whi + (size_t)nrow * HIDN + kt * 32 + q * 8);
      bfrag[kt] = *(const bf16x8*)p;
    }
  }

  for (int s = 0; s < T_SEQ + 3; ++s) {
    const int t = s - STAGE;
    const bool active = (t >= 0) && (t < T_SEQ);
    if (active) {
      f32x4 acc[4];
#pragma unroll
      for (int mt = 0; mt < 4; ++mt) acc[mt] = (f32x4){0.f, 0.f, 0.f, 0.f};

      auto stage_chunk = [&](int c) {
        u16* dst = sm->Ach[c & 1];
#pragma unroll
        for (int rep = 0; rep < 2; ++rep) {
          int id = tid + rep * 512;
          int r = id >> 4, a = id & 15;        // row (batch) / 16B atom
          uint4 v;
          if (STAGE == 0 && c < 4) {
            const float* xp = x + ((size_t)(r * T_SEQ + t)) * INW + c * 128 + a * 8;
            float4 f0 = *(const float4*)xp;
            float4 f1 = *(const float4*)(xp + 4);
            v.x = pack2(f0.x, f0.y); v.y = pack2(f0.z, f0.w);
            v.z = pack2(f1.x, f1.y); v.w = pack2(f1.z, f1.w);
          } else {
            const u16* src; int koff;
            if constexpr (STAGE == 0)      { src = ringOwn + ((t + 1) & 1) * SLOT_ELEMS; koff = (c - 4) * 128; }
            else if constexpr (STAGE == 3) { src = ringIn  + (t & 1) * SLOT_ELEMS;       koff = c * 128; }
            else {
              if (c < 6) { src = ringIn  + (t & 1) * SLOT_ELEMS;       koff = c * 128; }
              else       { src = ringOwn + ((t + 1) & 1) * SLOT_ELEMS; koff = (c - 6) * 128; }
            }
            v = *(const uint4*)(src + (size_t)r * HIDN + koff + a * 8);
          }
          int sa = a ^ (r & 7);                // depth-8 bank swizzle
          *(uint4*)((char*)dst + r * 256 + sa * 16) = v;
        }
      };

      stage_chunk(0);
      __syncthreads();
#pragma unroll
      for (int c = 0; c < NCH; ++c) {
        if (c + 1 < NCH) stage_chunk(c + 1);   // overlap next-chunk staging
        const bool mine = (STAGE == 3) ? (w < 7) : (kh == 0 ? (c < HALF) : (c >= HALF));
        if (mine) {
          const int kbase = ((STAGE == 3 || c < HALF) ? c : c - HALF) * 4;  // compile-time under unroll
          const char* Ab = (const char*)sm->Ach[c & 1];
#pragma unroll
          for (int kt2 = 0; kt2 < 4; ++kt2) {
            bf16x8 af[4];
#pragma unroll
            for (int mt = 0; mt < 4; ++mt) {
              int r = mt * 16 + l15;
              int a = kt2 * 4 + q;
              int sa = a ^ (r & 7);
              af[mt] = *(const bf16x8*)(Ab + r * 256 + sa * 16);
            }
#pragma unroll
            for (int mt = 0; mt < 4; ++mt)
              acc[mt] = __builtin_amdgcn_mfma_f32_16x16x32_bf16(af[mt], bfrag[kbase + kt2], acc[mt], 0, 0, 0);
          }
        }
        __syncthreads();
      }

      if constexpr (STAGE < 3) {
        // ---- K-half reduction via LDS ----
        if (kh == 1) {
#pragma unroll
          for (int mt = 0; mt < 4; ++mt)
#pragma unroll
            for (int i = 0; i < 4; ++i)
              sm->Xg[w * 1024 + (mt * 16 + q * 4 + i) * 16 + l15] = acc[mt][i];
        }
        __syncthreads();
        if (kh == 0) {
#pragma unroll
          for (int mt = 0; mt < 4; ++mt)
#pragma unroll
            for (int i = 0; i < 4; ++i) {
              int idx = (mt * 16 + q * 4 + i) * 16 + l15;
              sm->Xg[g * 1024 + idx] = acc[mt][i] + sm->Xg[(4 + g) * 1024 + idx];
            }
        }
        __syncthreads();
        // ---- gate nonlinearity + cell update + h/sum ring writes ----
        {
          int b = tid >> 3, jp = tid & 7;
          float hv[2];
#pragma unroll
          for (int u = 0; u < 2; ++u) {
            int j = jp * 2 + u;
            float pi = sm->Xg[0 * 1024 + b * 16 + j] + sm->bias_lds[j];
            float pf = sm->Xg[1 * 1024 + b * 16 + j] + sm->bias_lds[16 + j];
            float pg = sm->Xg[2 * 1024 + b * 16 + j] + sm->bias_lds[32 + j];
            float po = sm->Xg[3 * 1024 + b * 16 + j] + sm->bias_lds[48 + j];
            float ig = sigf(pi), fg = sigf(pf), gv = tanhf_(pg), og = sigf(po);
            float cc = fg * sm->c_lds[b * 16 + j] + ig * gv;
            sm->c_lds[b * 16 + j] = cc;
            hv[u] = og * tanhf_(cc);
          }
          int dw = (b * HIDN + j0 + jp * 2) >> 1;
          ((u32*)(ringOwn + (t & 1) * SLOT_ELEMS))[dw] = pack2(hv[0], hv[1]);
          if constexpr (STAGE == 1 || STAGE == 2) {
            u32 rv = ((const u32*)(ringRes + (t & 1) * SLOT_ELEMS))[dw];
            float s0 = b2f((u16)(rv & 0xffffu)) + hv[0];
            float s1 = b2f((u16)(rv >> 16)) + hv[1];
            ((u32*)(ringSum + (t & 1) * SLOT_ELEMS))[dw] = pack2(s0, s1);
          }
        }
      } else {
        // ---- projection store ----
        if (w < 7) {
#pragma unroll
          for (int mt = 0; mt < 4; ++mt)
#pragma unroll
            for (int i = 0; i < 4; ++i) {
              int b = mt * 16 + q * 4 + i;
              int n = w * 16 + l15;
              if (n < NOUT)
                out[((size_t)b * T_SEQ + t) * NOUT + n] = acc[mt][i];
            }
        }
      }
    }
    grid_barrier(flags, release, wg, (u32)(s + 1));
  }
}

__global__ __launch_bounds__(512, 2) void lstm_main(
    const float* __restrict__ x,
    const float* __restrict__ b1, const float* __restrict__ b2, const float* __restrict__ b3,
    const u16* __restrict__ wb, u16* __restrict__ rings, u32* __restrict__ bar,
    float* __restrict__ out) {
  __shared__ SharedMem sm;
  const int wg = blockIdx.x;
  const u16* Wih1b = wb + OFF_WIH1;
  const u16* Whh1b = wb + OFF_WHH1;
  const u16* Wih2b = wb + OFF_WIH2;
  const u16* Whh2b = wb + OFF_WHH2;
  const u16* Wih3b = wb + OFF_WIH3;
  const u16* Whh3b = wb + OFF_WHH3;
  const u16* Wpb   = wb + OFF_WP;
  u16* ring1  = rings;
  u16* ring2  = rings + 1 * RING_ELEMS;
  u16* ringS2 = rings + 2 * RING_ELEMS;
  u16* ring3  = rings + 3 * RING_ELEMS;
  u16* ringS3 = rings + 4 * RING_ELEMS;
  u32* flags   = bar;
  u32* release = bar + 256;
  if (wg < 48)
    stage_loop<0>(&sm, x, b1, Wih1b, Whh1b, nullptr, ring1, nullptr, nullptr, nullptr,
                  flags, release, wg, wg * 16);
  else if (wg < 96)
    stage_loop<1>(&sm, nullptr, b2, Wih2b, Whh2b, ring1, ring2, ring1, ringS2, nullptr,
                  flags, release, wg, (wg - 48) * 16);
  else if (wg < 144)
    stage_loop<2>(&sm, nullptr, b3, Wih3b, Whh3b, ringS2, ring3, ringS2, ringS3, nullptr,
                  flags, release, wg, (wg - 96) * 16);
  else
    stage_loop<3>(&sm, nullptr, nullptr, Wpb, nullptr, ringS3, nullptr, nullptr, nullptr,
                  (float*)out, flags, release, wg, 0);
}

extern "C" void kernel_launch(void* const* d_in, const int* in_sizes, int n_in,
                              void* d_out, int out_size, void* d_ws, size_t ws_size,
                              hipStream_t stream) {
  (void)in_sizes; (void)n_in; (void)out_size; (void)ws_size;
  const float* x    = (const float*)d_in[0];
  const float* Wih1 = (const float*)d_in[1];
  const float* Whh1 = (const float*)d_in[2];
  const float* b1   = (const float*)d_in[3];
  const float* Wih2 = (const float*)d_in[4];
  const float* Whh2 = (const float*)d_in[5];
  const float* b2   = (const float*)d_in[6];
  const float* Wih3 = (const float*)d_in[7];
  const float* Whh3 = (const float*)d_in[8];
  const float* b3   = (const float*)d_in[9];
  const float* Wp   = (const float*)d_in[10];

  char* base  = (char*)d_ws;
  u16*  wb    = (u16*)base;
  u16*  rings = (u16*)(base + RING_BYTE_OFF);
  u32*  bar   = (u32*)(base + RING_BYTE_OFF + RINGS_BYTES);

  // zero rings + barrier flags (ws is poisoned before every launch)
  hipMemsetAsync(base + RING_BYTE_OFF, 0, RINGS_BYTES + BAR_BYTES, stream);

  prep_weights<<<(W_TOTAL + 255) / 256, 256, 0, stream>>>(Wih1, Whh1, Wih2, Whh2, Wih3, Whh3, Wp, wb);

  lstm_main<<<NWG, 512, 0, stream>>>(x, b1, b2, b3, wb, rings, bar, (float*)d_out);
}